// Round 12
// baseline (191.134 us; speedup 1.0000x reference)
//
#include <hip/hip_runtime.h>
#include <hip/hip_bf16.h>
#include <math.h>

#define BB   2
#define NN   2048
#define DDIM 512
#define HH   8
#define DH   64
#define MTOT (BB*NN)      // 4096
#define EE   (BB*HH*NN*DH)   // 2,097,152 elems per Q/K/V-like array
#define WN   (DDIM*DDIM)     // 262,144 elems per weight
#define CPB  144             // chunk-blocks per bh (sum over qt of ceil((qt+1)/4))
#define NSLOT (BB*HH*CPB)    // 2304 partial slots

typedef __attribute__((ext_vector_type(8))) short bf16x8;   // 8 bf16 = 4 VGPRs
typedef __attribute__((ext_vector_type(4))) float f32x4;

__device__ __forceinline__ float softplus_f(float x) {
    return x > 20.f ? x : log1pf(expf(x));
}
__device__ __forceinline__ unsigned short f2bf(float x) {   // round-to-nearest-even
    union { float f; unsigned u; } v; v.f = x;
    unsigned r = v.u + 0x7fffu + ((v.u >> 16) & 1u);
    return (unsigned short)(r >> 16);
}
__device__ __forceinline__ float bf2f(unsigned short h) {
    union { unsigned u; float f; } v; v.u = ((unsigned)h) << 16; return v.f;
}
__device__ __forceinline__ void split4(float4 v, ushort4& h, ushort4& l) {
    h.x = f2bf(v.x); l.x = f2bf(v.x - bf2f(h.x));
    h.y = f2bf(v.y); l.y = f2bf(v.y - bf2f(h.y));
    h.z = f2bf(v.z); l.z = f2bf(v.z - bf2f(h.z));
    h.w = f2bf(v.w); l.w = f2bf(v.w - bf2f(h.w));
}
__device__ __forceinline__ ushort4 pk4(float a, float b, float c, float d) {
    union { __hip_bfloat162 b2[2]; ushort4 u4; } u;
    u.b2[0] = __float22bfloat162_rn(make_float2(a, b));   // v_cvt_pk_bf16_f32
    u.b2[1] = __float22bfloat162_rn(make_float2(c, d));
    return u.u4;
}

// ---------------------------------------------------------------------------
// One-time splits: Wq/Wk/Wv -> bf16 hi+lo, Wo -> bf16, x -> bf16 hi+lo.
// (Round-12: x added — round-11 re-split x inside every mm_proj block,
//  12x redundant VALU in the hot staging path.)
// ---------------------------------------------------------------------------
__global__ __launch_bounds__(256)
void split_all(const float* __restrict__ x,
               const float* __restrict__ Wq, const float* __restrict__ Wk,
               const float* __restrict__ Wv, const float* __restrict__ Wo,
               unsigned short* __restrict__ xh, unsigned short* __restrict__ xl,
               unsigned short* __restrict__ Whi, unsigned short* __restrict__ Wlo,
               unsigned short* __restrict__ Wob)
{
    const int y = blockIdx.y;
    if (y < 3) {
        const float* src = (y == 0) ? Wq : ((y == 1) ? Wk : Wv);
        const int i = blockIdx.x * 256 + threadIdx.x;
        float4 v = *(const float4*)(src + 4 * (size_t)i);
        ushort4 h, l;
        split4(v, h, l);
        *(ushort4*)(Whi + (size_t)y * WN + 4 * (size_t)i) = h;
        *(ushort4*)(Wlo + (size_t)y * WN + 4 * (size_t)i) = l;
    } else if (y == 3) {
        const int i = blockIdx.x * 256 + threadIdx.x;
        float4 v = *(const float4*)(Wo + 4 * (size_t)i);
        *(ushort4*)(Wob + 4 * (size_t)i) = pk4(v.x, v.y, v.z, v.w);
    } else {
        for (int i = blockIdx.x * 256 + threadIdx.x; i < EE / 4; i += 256 * 256) {
            float4 v = *(const float4*)(x + 4 * (size_t)i);
            ushort4 h, l;
            split4(v, h, l);
            *(ushort4*)(xh + 4 * (size_t)i) = h;
            *(ushort4*)(xl + 4 * (size_t)i) = l;
        }
    }
}

// ---------------------------------------------------------------------------
// Q/K/V projection GEMM. A = pre-split x bf16 hi/lo, B = pre-split W bf16.
// Modes 0/1 (Q,K): hi/lo compensated (3 MFMA) + fused norms. Mode 2 (V):
// plain bf16 (1 MFMA), Vt written transposed.
// ---------------------------------------------------------------------------
__global__ __launch_bounds__(256, 3)
void mm_proj(const unsigned short* __restrict__ Xh, const unsigned short* __restrict__ Xl,
             const unsigned short* __restrict__ Whi, const unsigned short* __restrict__ Wlo,
             unsigned short* __restrict__ Qhi, unsigned short* __restrict__ Qlo,
             unsigned short* __restrict__ Khi, unsigned short* __restrict__ Klo,
             unsigned short* __restrict__ Vt,
             float* __restrict__ QN, float* __restrict__ KN)
{
    const int mode = blockIdx.z;
    const unsigned short* Wh = Whi + (size_t)mode * WN;
    const unsigned short* Wl = Wlo + (size_t)mode * WN;
    const int m0 = blockIdx.x * 64, n0 = blockIdx.y * 128;

    __shared__ unsigned short Ah_s[4 * 64 * 8];    // [kq][64][8]
    __shared__ unsigned short Al_s[4 * 64 * 8];
    __shared__ unsigned short Bh_s[4 * 128 * 8];   // [kq][128][8]
    __shared__ unsigned short Bl_s[4 * 128 * 8];

    const int tid  = threadIdx.x;
    const int lane = tid & 63, lx = lane & 15, q4 = lane >> 4;
    const int w = tid >> 6, wm = w & 1, wn = w >> 1;
    const int rowA = tid & 63, kqA = tid >> 6;
    const int rowB = tid & 127, kbB = tid >> 7;

    f32x4 acc[2][4];
    #pragma unroll
    for (int mt = 0; mt < 2; ++mt)
        #pragma unroll
        for (int nt = 0; nt < 4; ++nt)
            acc[mt][nt] = (f32x4){0.f, 0.f, 0.f, 0.f};

    const int am = m0 + rowA;
    const size_t brow = (size_t)(n0 + rowB) * DDIM;

    uint4 rah, ral, rbh0, rbh1, rbl0, rbl1;
    {
        const size_t aoff = (size_t)am * DDIM + kqA * 8;
        rah = *(const uint4*)(Xh + aoff);
        if (mode != 2) ral = *(const uint4*)(Xl + aoff);
        const int eb = kbB * 8;
        rbh0 = *(const uint4*)(Wh + brow + eb);
        rbh1 = *(const uint4*)(Wh + brow + eb + 16);
        if (mode != 2) {
            rbl0 = *(const uint4*)(Wl + brow + eb);
            rbl1 = *(const uint4*)(Wl + brow + eb + 16);
        }
    }

    for (int k0 = 0; k0 < DDIM; k0 += 32) {
        __syncthreads();
        {
            const int off = (kqA << 9) + (rowA << 3);
            *(uint4*)&Ah_s[off] = rah;
            if (mode != 2) *(uint4*)&Al_s[off] = ral;
            const int offb  = (kbB << 10) + (rowB << 3);
            const int offb2 = ((kbB + 2) << 10) + (rowB << 3);
            *(uint4*)&Bh_s[offb]  = rbh0;
            *(uint4*)&Bh_s[offb2] = rbh1;
            if (mode != 2) {
                *(uint4*)&Bl_s[offb]  = rbl0;
                *(uint4*)&Bl_s[offb2] = rbl1;
            }
        }
        __syncthreads();

        if (k0 + 32 < DDIM) {
            const size_t aoff = (size_t)am * DDIM + k0 + 32 + kqA * 8;
            rah = *(const uint4*)(Xh + aoff);
            if (mode != 2) ral = *(const uint4*)(Xl + aoff);
            const int eb = k0 + 32 + kbB * 8;
            rbh0 = *(const uint4*)(Wh + brow + eb);
            rbh1 = *(const uint4*)(Wh + brow + eb + 16);
            if (mode != 2) {
                rbl0 = *(const uint4*)(Wl + brow + eb);
                rbl1 = *(const uint4*)(Wl + brow + eb + 16);
            }
        }

        bf16x8 fah[2], fal[2], fbh[4], fbl[4];
        #pragma unroll
        for (int mt = 0; mt < 2; ++mt) {
            const int off = (q4 << 9) + ((wm * 32 + mt * 16 + lx) << 3);
            fah[mt] = *(const bf16x8*)&Ah_s[off];
            if (mode != 2) fal[mt] = *(const bf16x8*)&Al_s[off];
        }
        #pragma unroll
        for (int nt = 0; nt < 4; ++nt) {
            const int off = (q4 << 10) + ((wn * 64 + nt * 16 + lx) << 3);
            fbh[nt] = *(const bf16x8*)&Bh_s[off];
            if (mode != 2) fbl[nt] = *(const bf16x8*)&Bl_s[off];
        }
        #pragma unroll
        for (int mt = 0; mt < 2; ++mt)
            #pragma unroll
            for (int nt = 0; nt < 4; ++nt) {
                acc[mt][nt] = __builtin_amdgcn_mfma_f32_16x16x32_bf16(fah[mt], fbh[nt], acc[mt][nt], 0, 0, 0);
                if (mode != 2) {
                    acc[mt][nt] = __builtin_amdgcn_mfma_f32_16x16x32_bf16(fah[mt], fbl[nt], acc[mt][nt], 0, 0, 0);
                    acc[mt][nt] = __builtin_amdgcn_mfma_f32_16x16x32_bf16(fal[mt], fbh[nt], acc[mt][nt], 0, 0, 0);
                }
            }
    }

    // ---- fused row norms (modes 0/1; wave's wn-half spans one head) ----
    if (mode == 0 || mode == 1) {
        float* Np = (mode == 0) ? QN : KN;
        const int head = (n0 + wn * 64) >> 6;
        #pragma unroll
        for (int mt = 0; mt < 2; ++mt)
            #pragma unroll
            for (int r = 0; r < 4; ++r) {
                float s = 0.f;
                #pragma unroll
                for (int nt = 0; nt < 4; ++nt) s = fmaf(acc[mt][nt][r], acc[mt][nt][r], s);
                s += __shfl_xor(s, 1);
                s += __shfl_xor(s, 2);
                s += __shfl_xor(s, 4);
                s += __shfl_xor(s, 8);
                if (lx == 0) {
                    const int m = m0 + wm * 32 + mt * 16 + q4 * 4 + r;
                    Np[(size_t)((m >> 11) * HH + head) * NN + (m & 2047)] = s;
                }
            }
    }

    // ---- epilogue (C row m = q4*4+reg, col j = lx) ----
    if (mode == 2) {
        #pragma unroll
        for (int mt = 0; mt < 2; ++mt) {
            const int mb = m0 + wm * 32 + mt * 16 + q4 * 4;
            const int b = mb >> 11, nb = mb & 2047;
            #pragma unroll
            for (int nt = 0; nt < 4; ++nt) {
                const int j = n0 + wn * 64 + nt * 16 + lx;
                ushort4 pv = pk4(acc[mt][nt][0], acc[mt][nt][1],
                                 acc[mt][nt][2], acc[mt][nt][3]);
                *(ushort4*)(Vt + ((size_t)(b * HH + (j >> 6)) * 64 + (j & 63)) * NN + nb) = pv;
            }
        }
    } else {
        #pragma unroll
        for (int mt = 0; mt < 2; ++mt) {
            #pragma unroll
            for (int r = 0; r < 4; ++r) {
                const int m = m0 + wm * 32 + mt * 16 + q4 * 4 + r;
                const int b = m >> 11, n2 = m & 2047;
                #pragma unroll
                for (int nt = 0; nt < 4; ++nt) {
                    const int j = n0 + wn * 64 + nt * 16 + lx;
                    const float v = acc[mt][nt][r];
                    const size_t idx = (((size_t)(b * HH + (j >> 6)) * NN + n2) << 6) + (j & 63);
                    const unsigned short h = f2bf(v);
                    const unsigned short l = f2bf(v - bf2f(h));
                    if (mode == 0) { Qhi[idx] = h; Qlo[idx] = l; }
                    else           { Khi[idx] = h; Klo[idx] = l; }
                }
            }
        }
    }
}

// ---------------------------------------------------------------------------
// Output projection, plain bf16: out = AO @ Wo^T. B = pre-split Wo bf16.
// ---------------------------------------------------------------------------
__global__ __launch_bounds__(256, 4)
void mm_out(const unsigned short* __restrict__ AO, const unsigned short* __restrict__ Wob,
            float* __restrict__ Outp)
{
    const int m0 = blockIdx.x * 64, n0 = blockIdx.y * 64;

    __shared__ unsigned short Ah_s[4 * 64 * 8];    // [kq][64][8]
    __shared__ unsigned short Bh_s[4 * 64 * 8];

    const int tid  = threadIdx.x;
    const int lane = tid & 63, lx = lane & 15, q4 = lane >> 4;
    const int w = tid >> 6, wm = w & 1, wn = w >> 1;
    const int rowA = tid & 63, kqA = tid >> 6;

    f32x4 acc[2][2];
    #pragma unroll
    for (int mt = 0; mt < 2; ++mt)
        #pragma unroll
        for (int nt = 0; nt < 2; ++nt)
            acc[mt][nt] = (f32x4){0.f, 0.f, 0.f, 0.f};

    const int am = m0 + rowA;
    const int ab = am >> 11, an = am & 2047;
    const size_t brow = (size_t)(n0 + rowA) * DDIM;

    uint4 rah, rbh;
    {
        const int e = kqA * 8;
        rah = *(const uint4*)(AO + (((size_t)(ab * HH + (e >> 6)) * NN + an) << 6) + (e & 63));
        rbh = *(const uint4*)(Wob + brow + e);
    }

    for (int k0 = 0; k0 < DDIM; k0 += 32) {
        __syncthreads();
        {
            const int off = (kqA << 9) + (rowA << 3);
            *(uint4*)&Ah_s[off] = rah;
            *(uint4*)&Bh_s[off] = rbh;
        }
        __syncthreads();

        if (k0 + 32 < DDIM) {
            const int e = k0 + 32 + kqA * 8;
            rah = *(const uint4*)(AO + (((size_t)(ab * HH + (e >> 6)) * NN + an) << 6) + (e & 63));
            rbh = *(const uint4*)(Wob + brow + e);
        }

        bf16x8 fah[2], fbh[2];
        #pragma unroll
        for (int mt = 0; mt < 2; ++mt)
            fah[mt] = *(const bf16x8*)&Ah_s[(q4 << 9) + ((wm * 32 + mt * 16 + lx) << 3)];
        #pragma unroll
        for (int nt = 0; nt < 2; ++nt)
            fbh[nt] = *(const bf16x8*)&Bh_s[(q4 << 9) + ((wn * 32 + nt * 16 + lx) << 3)];
        #pragma unroll
        for (int mt = 0; mt < 2; ++mt)
            #pragma unroll
            for (int nt = 0; nt < 2; ++nt)
                acc[mt][nt] = __builtin_amdgcn_mfma_f32_16x16x32_bf16(fah[mt], fbh[nt], acc[mt][nt], 0, 0, 0);
    }

    #pragma unroll
    for (int mt = 0; mt < 2; ++mt)
        #pragma unroll
        for (int r = 0; r < 4; ++r) {
            const int m = m0 + wm * 32 + mt * 16 + q4 * 4 + r;
            #pragma unroll
            for (int nt = 0; nt < 2; ++nt)
                Outp[(size_t)m * DDIM + n0 + wn * 32 + nt * 16 + lx] = acc[mt][nt][r];
        }
}

// ---------------------------------------------------------------------------
// MFMA flash attention, split-K, S^T formulation. Round-12: fast sqrt
// (__builtin_amdgcn_sqrtf = 1x v_sqrt_f32 vs ~10-instr IEEE sequence) and
// per-key invariants (sumn, betaL^2*(1+c*sumn)) hoisted out of the score loop
// — the kernel is VALU-issue bound (5.2k cyc/block-iter, 2.9k VALU).
// ---------------------------------------------------------------------------
__global__ __launch_bounds__(256, 4)
void attn_mfma(const unsigned short* __restrict__ Qhi, const unsigned short* __restrict__ Qlo,
               const unsigned short* __restrict__ Khi, const unsigned short* __restrict__ Klo,
               const unsigned short* __restrict__ Vt,
               const float* __restrict__ QN, const float* __restrict__ KN,
               const float* __restrict__ pLC, const float* __restrict__ pLB,
               unsigned short* __restrict__ Opart, float* __restrict__ Mp, float* __restrict__ Lp)
{
    __shared__ unsigned short Kh_s[8 * 64 * 8];   // [dchunk][key][8]
    __shared__ unsigned short Kl_s[8 * 64 * 8];
    __shared__ unsigned short Vt_s[8 * 64 * 8];   // [keychunk][d][8]
    __shared__ unsigned short P_s [8 * 64 * 8];   // [keychunk][qrow][8]
    __shared__ __align__(16) float kn_s[64];
    __shared__ float qn_s[64];

    // decode (qt, chunk): group g = qt>>2 has C=g+1 chunks/qt, base 2g(g+1)
    const int idx = blockIdx.x;
    const int g   = (idx >= 112) ? 7 : (idx >= 84) ? 6 : (idx >= 60) ? 5 :
                    (idx >= 40) ? 4 : (idx >= 24) ? 3 : (idx >= 12) ? 2 :
                    (idx >= 4)  ? 1 : 0;
    const int rem = idx - 2 * g * (g + 1);
    const int C   = g + 1;
    const int qt  = g * 4 + rem / C;
    const int c0  = rem % C;
    const int bh  = blockIdx.y;
    const int nk  = qt + 1;
    const int kt0  = (c0 * nk) / C;        // balanced ranges (len 2..4)
    const int kend = ((c0 + 1) * nk) / C;

    const int tid  = threadIdx.x;
    const int w    = tid >> 6;
    const int lane = tid & 63;
    const int lx   = lane & 15;
    const int q4   = lane >> 4;
    const int qrl  = w * 16 + lx;          // this thread's (single) local q-row

    const float hc    = softplus_f(pLC[0]);
    const float betaL = (softplus_f(pLB[0]) + 0.5f) * 1.44269504f;  // log2 domain
    const float b2    = betaL * betaL;

    const size_t base = ((size_t)bh * NN) << 6;

    // Q fragments (lane holds row qt*64+qrl, k-chunk q4*8) — serve as B operand
    const unsigned short* qrh = Qhi + base + ((size_t)(qt * 64 + qrl) << 6) + q4 * 8;
    const unsigned short* qrl_p = Qlo + base + ((size_t)(qt * 64 + qrl) << 6) + q4 * 8;
    const bf16x8 qh0 = *(const bf16x8*)(qrh);
    const bf16x8 qh1 = *(const bf16x8*)(qrh + 32);
    const bf16x8 ql0 = *(const bf16x8*)(qrl_p);
    const bf16x8 ql1 = *(const bf16x8*)(qrl_p + 32);

    if (tid < 64) qn_s[tid] = QN[(size_t)bh * NN + qt * 64 + tid];

    f32x4 Oacc[4];     // O^T: d = t2*16+q4*4+r, qrow = qrl
    #pragma unroll
    for (int t = 0; t < 4; ++t) Oacc[t] = (f32x4){0.f, 0.f, 0.f, 0.f};
    float m_st = -INFINITY, l_st = 0.f;

    const int sc = tid >> 6, sr = tid & 63;

    // prefetch first tile (kt0)
    uint4 pKh0, pKh1, pKl0, pKl1, pVt0, pVt1; float pkn = 0.f;
    {
        const unsigned short* kh = Khi + base + ((size_t)(kt0 * 64 + sr) << 6) + sc * 8;
        const unsigned short* kl = Klo + base + ((size_t)(kt0 * 64 + sr) << 6) + sc * 8;
        const unsigned short* vt = Vt  + base + (size_t)sr * NN + kt0 * 64 + sc * 8;
        pKh0 = *(const uint4*)(kh);  pKh1 = *(const uint4*)(kh + 32);
        pKl0 = *(const uint4*)(kl);  pKl1 = *(const uint4*)(kl + 32);
        pVt0 = *(const uint4*)(vt);  pVt1 = *(const uint4*)(vt + 32);
        if (tid < 64) pkn = KN[(size_t)bh * NN + kt0 * 64 + tid];
    }

    __syncthreads();   // qn_s visible
    const float qn = qn_s[qrl];

    for (int kt = kt0; kt < kend; ++kt) {
        // ---- commit prefetched tile (lane-contiguous, conflict-free) ----
        const int soff = (sc << 9) + (sr << 3);
        *(uint4*)&Kh_s[soff]            = pKh0;
        *(uint4*)&Kh_s[soff + (4 << 9)] = pKh1;
        *(uint4*)&Kl_s[soff]            = pKl0;
        *(uint4*)&Kl_s[soff + (4 << 9)] = pKl1;
        *(uint4*)&Vt_s[soff]            = pVt0;
        *(uint4*)&Vt_s[soff + (4 << 9)] = pVt1;
        if (tid < 64) kn_s[tid] = pkn;
        __syncthreads();

        // ---- prefetch tile kt+1 ----
        if (kt + 1 < kend) {
            const unsigned short* kh = Khi + base + ((size_t)((kt + 1) * 64 + sr) << 6) + sc * 8;
            const unsigned short* kl = Klo + base + ((size_t)((kt + 1) * 64 + sr) << 6) + sc * 8;
            const unsigned short* vt = Vt  + base + (size_t)sr * NN + (kt + 1) * 64 + sc * 8;
            pKh0 = *(const uint4*)(kh);  pKh1 = *(const uint4*)(kh + 32);
            pKl0 = *(const uint4*)(kl);  pKl1 = *(const uint4*)(kl + 32);
            pVt0 = *(const uint4*)(vt);  pVt1 = *(const uint4*)(vt + 32);
            if (tid < 64) pkn = KN[(size_t)bh * NN + (kt + 1) * 64 + tid];
        }

        // ---- S^T = K Q^T (hi/lo compensated): A = K rows, B = Q rows ----
        f32x4 S[4];    // S[t][r]: key = t*16 + q4*4 + r, qrow = qrl
        #pragma unroll
        for (int t = 0; t < 4; ++t) {
            f32x4 acc = (f32x4){0.f, 0.f, 0.f, 0.f};
            #pragma unroll
            for (int c2 = 0; c2 < 2; ++c2) {
                const int off = ((c2 * 4 + q4) << 9) + ((t * 16 + lx) << 3);
                const bf16x8 kh = *(const bf16x8*)&Kh_s[off];
                const bf16x8 kl = *(const bf16x8*)&Kl_s[off];
                const bf16x8 qh = c2 ? qh1 : qh0;
                const bf16x8 ql = c2 ? ql1 : ql0;
                acc = __builtin_amdgcn_mfma_f32_16x16x32_bf16(kh, qh, acc, 0, 0, 0);
                acc = __builtin_amdgcn_mfma_f32_16x16x32_bf16(kh, ql, acc, 0, 0, 0);
                acc = __builtin_amdgcn_mfma_f32_16x16x32_bf16(kl, qh, acc, 0, 0, 0);
            }
            S[t] = acc;
        }

        // ---- per-key invariants (hoisted): sumn, w = betaL^2*(1+c*sumn) ----
        float sn16[16], w16[16];
        #pragma unroll
        for (int t = 0; t < 4; ++t) {
            float kn4[4];
            *(float4*)kn4 = *(const float4*)&kn_s[t * 16 + q4 * 4];
            #pragma unroll
            for (int r = 0; r < 4; ++r) {
                const float sn = qn + kn4[r];
                sn16[t * 4 + r] = sn;
                w16[t * 4 + r]  = b2 * fmaf(hc, sn, 1.f);
            }
        }

        // ---- scores: s = -sqrt(w * max(sumn - 2S, 0)), log2 domain ----
        const bool diag = (kt == qt);
        float mloc = -INFINITY;
        #pragma unroll
        for (int t = 0; t < 4; ++t) {
            #pragma unroll
            for (int r = 0; r < 4; ++r) {
                const float diff = fmaxf(fmaf(-2.f, S[t][r], sn16[t * 4 + r]), 0.f);
                float s = -__builtin_amdgcn_sqrtf(diff * w16[t * 4 + r]);
                if (diag && (t * 16 + q4 * 4 + r) > qrl) s = -INFINITY;
                S[t][r] = s;
                mloc = fmaxf(mloc, s);
            }
        }
        mloc = fmaxf(mloc, __shfl_xor(mloc, 16));
        mloc = fmaxf(mloc, __shfl_xor(mloc, 32));
        const float mn = fmaxf(m_st, mloc);
        const float al = exp2f(m_st - mn);
        m_st = mn;

        float rs = 0.f;
        #pragma unroll
        for (int t = 0; t < 4; ++t) {
            const float p0 = exp2f(S[t][0] - mn);
            const float p1 = exp2f(S[t][1] - mn);
            const float p2 = exp2f(S[t][2] - mn);
            const float p3 = exp2f(S[t][3] - mn);
            rs += (p0 + p1) + (p2 + p3);
            // keys t*16+q4*4+{0..3} are LDS-consecutive -> one b64 store
            *(ushort4*)&P_s[((2 * t + (q4 >> 1)) << 9) + (qrl << 3) + ((q4 & 1) << 2)] =
                pk4(p0, p1, p2, p3);
        }
        rs += __shfl_xor(rs, 16);
        rs += __shfl_xor(rs, 32);
        l_st = l_st * al + rs;
        #pragma unroll
        for (int t = 0; t < 4; ++t) {
            Oacc[t][0] *= al; Oacc[t][1] *= al;
            Oacc[t][2] *= al; Oacc[t][3] *= al;
        }

        // P_s rows qrl are wave-local; same-wave DS ops pipe-ordered.
        __builtin_amdgcn_wave_barrier();

        // ---- O^T += V^T P : A = Vt rows (d), B = P (qrow cols) ----
        #pragma unroll
        for (int c2 = 0; c2 < 2; ++c2) {
            const bf16x8 pb = *(const bf16x8*)&P_s[((c2 * 4 + q4) << 9) + (qrl << 3)];
            #pragma unroll
            for (int t2 = 0; t2 < 4; ++t2) {
                const bf16x8 va = *(const bf16x8*)&Vt_s[((c2 * 4 + q4) << 9) + ((t2 * 16 + lx) << 3)];
                Oacc[t2] = __builtin_amdgcn_mfma_f32_16x16x32_bf16(va, pb, Oacc[t2], 0, 0, 0);
            }
        }
        __syncthreads();   // all waves done reading K/Vt/P before next commit
    }

    // ---- epilogue: partial [qrow][d] bf16 + (m2, l); slot = per-bh idx ----
    const int slot = bh * CPB + idx;
    unsigned short* op = Opart + ((size_t)slot << 12);
    #pragma unroll
    for (int t2 = 0; t2 < 4; ++t2)
        *(ushort4*)&op[qrl * 64 + t2 * 16 + q4 * 4] =
            pk4(Oacc[t2][0], Oacc[t2][1], Oacc[t2][2], Oacc[t2][3]);
    if (q4 == 0) {
        Mp[slot * 64 + qrl] = m_st;   // log2 domain
        Lp[slot * 64 + qrl] = l_st;
    }
}

// ---------------------------------------------------------------------------
// Combine <=8 chunk partials per (bh, qt), log2-domain weights; AO bf16.
// ---------------------------------------------------------------------------
__global__ __launch_bounds__(256)
void attn_combine(const unsigned short* __restrict__ Opart, const float* __restrict__ Mp,
                  const float* __restrict__ Lp, unsigned short* __restrict__ AO)
{
    const int bh = blockIdx.x >> 5, qt = blockIdx.x & 31;
    const int g = qt >> 2, C = g + 1;
    const int first = 2 * g * (g + 1) + (qt & 3) * C;
    const int row = threadIdx.x >> 2, qd = threadIdx.x & 3;
    const int slot0 = bh * CPB + first;

    float m = -INFINITY;
    for (int c = 0; c < C; ++c) m = fmaxf(m, Mp[(slot0 + c) * 64 + row]);
    float L = 0.f;
    float o[16];
    #pragma unroll
    for (int j = 0; j < 16; ++j) o[j] = 0.f;

    for (int c = 0; c < C; ++c) {
        const float wgt = exp2f(Mp[(slot0 + c) * 64 + row] - m);
        L += wgt * Lp[(slot0 + c) * 64 + row];
        const unsigned short* op = Opart + (((size_t)(slot0 + c)) << 12) + row * 64 + qd * 16;
        union { uint4 v; unsigned short u[8]; } a0, a1;
        a0.v = *(const uint4*)(op);
        a1.v = *(const uint4*)(op + 8);
        #pragma unroll
        for (int j = 0; j < 8; ++j) {
            o[j]     = fmaf(wgt, bf2f(a0.u[j]), o[j]);
            o[j + 8] = fmaf(wgt, bf2f(a1.u[j]), o[j + 8]);
        }
    }

    const float inv = 1.f / L;
    const size_t obase = (((size_t)bh * NN + qt * 64 + row) << 6) + qd * 16;
    *(ushort4*)(AO + obase)      = pk4(o[0]*inv,  o[1]*inv,  o[2]*inv,  o[3]*inv);
    *(ushort4*)(AO + obase + 4)  = pk4(o[4]*inv,  o[5]*inv,  o[6]*inv,  o[7]*inv);
    *(ushort4*)(AO + obase + 8)  = pk4(o[8]*inv,  o[9]*inv,  o[10]*inv, o[11]*inv);
    *(ushort4*)(AO + obase + 12) = pk4(o[12]*inv, o[13]*inv, o[14]*inv, o[15]*inv);
}

// ---------------------------------------------------------------------------
extern "C" void kernel_launch(void* const* d_in, const int* in_sizes, int n_in,
                              void* d_out, int out_size, void* d_ws, size_t ws_size,
                              hipStream_t stream)
{
    const float* x        = (const float*)d_in[0];
    const float* Wq       = (const float*)d_in[1];
    const float* Wk       = (const float*)d_in[2];
    const float* Wv       = (const float*)d_in[3];
    const float* Wo       = (const float*)d_in[4];
    const float* log_c    = (const float*)d_in[5];
    const float* log_beta = (const float*)d_in[6];
    float* out = (float*)d_out;

    unsigned short* p = (unsigned short*)d_ws;
    unsigned short* Qhi = p;            p += EE;
    unsigned short* Qlo = p;            p += EE;
    unsigned short* Khi = p;            p += EE;
    unsigned short* Klo = p;            p += EE;
    unsigned short* Vtr = p;            p += EE;
    unsigned short* AO  = p;            p += EE;
    unsigned short* xh  = p;            p += EE;
    unsigned short* xl  = p;            p += EE;
    unsigned short* Whi = p;            p += 3 * (size_t)WN;
    unsigned short* Wlo = p;            p += 3 * (size_t)WN;
    unsigned short* Wob = p;            p += WN;
    unsigned short* Opart = p;          p += (size_t)NSLOT * 4096;
    float* QN = (float*)p;
    float* KN = QN + (size_t)BB * HH * NN;
    float* Mp = KN + (size_t)BB * HH * NN;
    float* Lp = Mp + (size_t)NSLOT * 64;

    split_all<<<dim3(WN / 1024, 5), 256, 0, stream>>>(x, Wq, Wk, Wv, Wo,
                                                      xh, xl, Whi, Wlo, Wob);
    mm_proj<<<dim3(MTOT / 64, DDIM / 128, 3), 256, 0, stream>>>(
        xh, xl, Whi, Wlo, Qhi, Qlo, Khi, Klo, Vtr, QN, KN);
    attn_mfma<<<dim3(CPB, 16), 256, 0, stream>>>(Qhi, Qlo, Khi, Klo, Vtr, QN, KN,
                                                 log_c, log_beta, Opart, Mp, Lp);
    attn_combine<<<dim3(512), 256, 0, stream>>>(Opart, Mp, Lp, AO);
    mm_out<<<dim3(MTOT / 64, DDIM / 64), 256, 0, stream>>>(AO, Wob, out);
}